// Round 3
// baseline (441.962 us; speedup 1.0000x reference)
//
#include <hip/hip_runtime.h>
#include <hip/hip_bf16.h>
#include <math.h>

// ---------------------------------------------------------------------------
// TransformerLayer: B=2 S=2048 D=1024 H=16 HD=64.
// I/O dtype: FLOAT32 (reference is jnp.float32; npz sizes confirm f32 wire
// format; 2%-of-max threshold). Internal compute: bf16 MFMA, f32 accumulate.
//   pe-add(f32->bf16) -> Q/K/V proj -> MHA (flash) -> Wo
//   -> LN(attn+q_pe) -> FFN relu(x@W1^T+b1)@W2^T+b2 -> LN(ff+x) -> f32 out
// ---------------------------------------------------------------------------

#define B_ 2
#define S_ 2048
#define D_ 1024
#define H_ 16
#define HD_ 64

typedef __bf16 bf16_t;
typedef __bf16 bf16x8 __attribute__((ext_vector_type(8)));
typedef __bf16 bf16x4v __attribute__((ext_vector_type(4)));
typedef float f32x4 __attribute__((ext_vector_type(4)));

__device__ __forceinline__ f32x4 mfma16(bf16x8 a, bf16x8 b, f32x4 c) {
  return __builtin_amdgcn_mfma_f32_16x16x32_bf16(a, b, c, 0, 0, 0);
}

// load 8 consecutive f32, convert to bf16x8 (RTNE via fptrunc)
__device__ __forceinline__ bf16x8 ldcvt8(const float* p) {
  float4 x0 = *(const float4*)p;
  float4 x1 = *(const float4*)(p + 4);
  bf16x8 r;
  r[0] = (bf16_t)x0.x; r[1] = (bf16_t)x0.y; r[2] = (bf16_t)x0.z; r[3] = (bf16_t)x0.w;
  r[4] = (bf16_t)x1.x; r[5] = (bf16_t)x1.y; r[6] = (bf16_t)x1.z; r[7] = (bf16_t)x1.w;
  return r;
}

// ---------------------------------------------------------------------------
// Kernel 1: positional encoding + add; f32 in -> bf16 out (q,k,v one pass).
// ---------------------------------------------------------------------------
__global__ __launch_bounds__(256) void addpe_kernel(
    const float* __restrict__ q, const float* __restrict__ k,
    const float* __restrict__ v,
    bf16_t* __restrict__ qo, bf16_t* __restrict__ ko, bf16_t* __restrict__ vo) {
  const int row = blockIdx.x;            // b*S + s
  const int s = row & (S_ - 1);
  const int d0 = threadIdx.x * 4;
  const size_t base = (size_t)row * D_ + d0;
  float pe[4];
#pragma unroll
  for (int p = 0; p < 2; ++p) {
    // -ln(10000)/1024 = -0.008994473019508
    float div = __expf((float)(d0 + 2 * p) * -0.008994473019508f);
    float ang = (float)s * div;
    pe[2 * p]     = sinf(ang);
    pe[2 * p + 1] = cosf(ang);
  }
  float4 qv = *(const float4*)&q[base];
  float4 kv = *(const float4*)&k[base];
  float4 vv = *(const float4*)&v[base];
  bf16x4v qr, kr, vr;
  qr[0] = (bf16_t)(qv.x + pe[0]); qr[1] = (bf16_t)(qv.y + pe[1]);
  qr[2] = (bf16_t)(qv.z + pe[2]); qr[3] = (bf16_t)(qv.w + pe[3]);
  kr[0] = (bf16_t)(kv.x + pe[0]); kr[1] = (bf16_t)(kv.y + pe[1]);
  kr[2] = (bf16_t)(kv.z + pe[2]); kr[3] = (bf16_t)(kv.w + pe[3]);
  vr[0] = (bf16_t)(vv.x + pe[0]); vr[1] = (bf16_t)(vv.y + pe[1]);
  vr[2] = (bf16_t)(vv.z + pe[2]); vr[3] = (bf16_t)(vv.w + pe[3]);
  *(bf16x4v*)&qo[base] = qr;
  *(bf16x4v*)&ko[base] = kr;
  *(bf16x4v*)&vo[base] = vr;
}

// ---------------------------------------------------------------------------
// Kernel 2: NT GEMM  C[M,N] = A[M,K] * W[N,K]^T
// A: bf16 activations. W: FLOAT32 weights (converted to bf16 during staging).
// 128x128 tile, BK=32, 4 waves. Register-staged LDS.
// EPI: 0 = none, 1 = +bias, 2 = +bias +relu  (bias is f32)
// ---------------------------------------------------------------------------
template <int EPI>
__global__ __launch_bounds__(256) void gemm_bt(
    const bf16_t* __restrict__ A, const float* __restrict__ W,
    const float* __restrict__ bias, bf16_t* __restrict__ C,
    int M, int N, int K) {
  __shared__ alignas(16) bf16_t As[128 * 32];   // [row][k] row-major [128][32]
  __shared__ alignas(16) bf16_t Bs[128 * 32];   // [ncol][k]
  const int t = threadIdx.x, lane = t & 63, wid = t >> 6;
  const int m0 = blockIdx.y * 128, n0 = blockIdx.x * 128;
  const int wr = wid >> 1, wc = wid & 1;

  const f32x4 zero = {0.f, 0.f, 0.f, 0.f};
  f32x4 acc[4][4];
#pragma unroll
  for (int m = 0; m < 4; ++m)
#pragma unroll
    for (int n = 0; n < 4; ++n) acc[m][n] = zero;

  // staging: thread t owns LDS elems [t*8, t*8+8) (rows 0..63) and
  // [2048+t*8 ...) (rows 64..127): row = t/4 (+64), col = (t%4)*8.
  const int srow = t >> 2;
  const int scol = (t & 3) * 8;
  const bf16_t* Ag0 = A + (size_t)(m0 + srow) * K + scol;
  const bf16_t* Ag1 = A + (size_t)(m0 + 64 + srow) * K + scol;
  const float*  Wg0 = W + (size_t)(n0 + srow) * K + scol;
  const float*  Wg1 = W + (size_t)(n0 + 64 + srow) * K + scol;

  for (int k0 = 0; k0 < K; k0 += 32) {
    bf16x8 a0 = *(const bf16x8*)(Ag0 + k0);
    bf16x8 a1 = *(const bf16x8*)(Ag1 + k0);
    bf16x8 w0 = ldcvt8(Wg0 + k0);
    bf16x8 w1 = ldcvt8(Wg1 + k0);
    __syncthreads();                      // prev iter's LDS reads complete
    *(bf16x8*)&As[t * 8]        = a0;
    *(bf16x8*)&As[2048 + t * 8] = a1;
    *(bf16x8*)&Bs[t * 8]        = w0;
    *(bf16x8*)&Bs[2048 + t * 8] = w1;
    __syncthreads();                      // writes visible to all waves

    bf16x8 af[4], bfr[4];
#pragma unroll
    for (int m = 0; m < 4; ++m)
      af[m] = *(const bf16x8*)&As[(wr * 64 + m * 16 + (lane & 15)) * 32 + (lane >> 4) * 8];
#pragma unroll
    for (int n = 0; n < 4; ++n)
      bfr[n] = *(const bf16x8*)&Bs[(wc * 64 + n * 16 + (lane & 15)) * 32 + (lane >> 4) * 8];
#pragma unroll
    for (int m = 0; m < 4; ++m)
#pragma unroll
      for (int n = 0; n < 4; ++n)
        acc[m][n] = mfma16(af[m], bfr[n], acc[m][n]);
  }

  // epilogue: D frag layout col = lane&15, row = (lane>>4)*4 + r
  const int rbase = m0 + wr * 64 + (lane >> 4) * 4;
  const int cbase = n0 + wc * 64 + (lane & 15);
#pragma unroll
  for (int n = 0; n < 4; ++n) {
    const int col = cbase + n * 16;
    float bv = (EPI >= 1) ? bias[col] : 0.f;
#pragma unroll
    for (int m = 0; m < 4; ++m) {
#pragma unroll
      for (int r = 0; r < 4; ++r) {
        float vv = acc[m][n][r] + bv;
        if (EPI == 2) vv = fmaxf(vv, 0.f);
        C[(size_t)(rbase + m * 16 + r) * N + col] = (bf16_t)vv;
      }
    }
  }
}

// ---------------------------------------------------------------------------
// Kernel 3: flash attention (all bf16). grid = (S/64, B*H), 4 waves,
// each wave owns 16 q-rows. KBLK=32, K/V reg-staged to LDS, online softmax.
// ---------------------------------------------------------------------------
__global__ __launch_bounds__(256) void attn_kernel(
    const bf16_t* __restrict__ Q, const bf16_t* __restrict__ K,
    const bf16_t* __restrict__ V, bf16_t* __restrict__ O) {
  __shared__ alignas(16) bf16_t Ks[32 * 64];
  __shared__ alignas(16) bf16_t Vs[32 * 64];
  __shared__ alignas(16) bf16_t Ps[4][16 * 32];
  const int t = threadIdx.x, lane = t & 63, wid = t >> 6;
  const int bh = blockIdx.y;
  const int b = bh >> 4, h = bh & 15;
  const int q0 = blockIdx.x * 64 + wid * 16;

  // Q fragments (A-operand): row = lane&15, d = (lane>>4)*8 + j (+32)
  const size_t rowQ = (size_t)(b * S_ + q0 + (lane & 15)) * D_ + h * HD_ + ((lane >> 4) * 8);
  const bf16x8 qa0 = *(const bf16x8*)&Q[rowQ];
  const bf16x8 qa1 = *(const bf16x8*)&Q[rowQ + 32];

  const f32x4 zero = {0.f, 0.f, 0.f, 0.f};
  f32x4 ctx[4] = {zero, zero, zero, zero};
  float mrow[4] = {-1e30f, -1e30f, -1e30f, -1e30f};
  float lrow[4] = {0.f, 0.f, 0.f, 0.f};

  // staging: thread t owns LDS elems [t*8, t*8+8): row = t/8, col = (t%8)*8
  const int srow = t >> 3;
  const int scol = (t & 7) * 8;
  const bf16_t* Kg = K + (size_t)(b * S_ + srow) * D_ + h * HD_ + scol;
  const bf16_t* Vg = V + (size_t)(b * S_ + srow) * D_ + h * HD_ + scol;

  for (int kt = 0; kt < S_ / 32; ++kt) {
    bf16x8 kreg = *(const bf16x8*)(Kg + (size_t)kt * 32 * D_);
    bf16x8 vreg = *(const bf16x8*)(Vg + (size_t)kt * 32 * D_);
    __syncthreads();                 // prev iter's LDS reads complete
    *(bf16x8*)&Ks[t * 8] = kreg;
    *(bf16x8*)&Vs[t * 8] = vreg;
    __syncthreads();                 // K/V tile visible

    // S tile (16q x 32k) as two 16x16 frags; mfma k-dim = head dim (2x32)
    f32x4 sf[2];
#pragma unroll
    for (int kc = 0; kc < 2; ++kc) {
      const int krow = kc * 16 + (lane & 15);
      bf16x8 kb0 = *(const bf16x8*)&Ks[krow * 64 + (lane >> 4) * 8];
      bf16x8 kb1 = *(const bf16x8*)&Ks[krow * 64 + 32 + (lane >> 4) * 8];
      f32x4 z = zero;
      z = mfma16(qa0, kb0, z);
      z = mfma16(qa1, kb1, z);
      sf[kc] = z;
    }

    // online softmax; lane group g=(lane>>4) owns q-rows g*4..g*4+3
#pragma unroll
    for (int r = 0; r < 4; ++r) {
      float s0 = sf[0][r] * 0.125f;   // 1/sqrt(64)
      float s1 = sf[1][r] * 0.125f;
      float mx = fmaxf(s0, s1);
#pragma unroll
      for (int o = 1; o < 16; o <<= 1) mx = fmaxf(mx, __shfl_xor(mx, o));
      float mnew = fmaxf(mrow[r], mx);
      float scl = __expf(mrow[r] - mnew);
      float p0 = __expf(s0 - mnew), p1 = __expf(s1 - mnew);
      float rs = p0 + p1;
#pragma unroll
      for (int o = 1; o < 16; o <<= 1) rs += __shfl_xor(rs, o);
      lrow[r] = lrow[r] * scl + rs;
      mrow[r] = mnew;
#pragma unroll
      for (int n = 0; n < 4; ++n) ctx[n][r] *= scl;
      const int prow = (lane >> 4) * 4 + r;
      Ps[wid][prow * 32 + (lane & 15)] = (bf16_t)p0;
      Ps[wid][prow * 32 + 16 + (lane & 15)] = (bf16_t)p1;
    }
    __syncthreads();                 // P visible

    // PV: A = P (16x32), B = V (32k x 16col) frags from Vs
    bf16x8 ap = *(const bf16x8*)&Ps[wid][(lane & 15) * 32 + (lane >> 4) * 8];
#pragma unroll
    for (int n = 0; n < 4; ++n) {
      bf16x8 vb;
#pragma unroll
      for (int j = 0; j < 8; ++j)
        vb[j] = Vs[((lane >> 4) * 8 + j) * 64 + n * 16 + (lane & 15)];
      ctx[n] = mfma16(ap, vb, ctx[n]);
    }
  }

  // write ctx / l  (D-frag layout: row=(lane>>4)*4+r, col=n*16+(lane&15))
#pragma unroll
  for (int r = 0; r < 4; ++r) {
    float inv = 1.f / lrow[r];
    const size_t ro = (size_t)(b * S_ + q0 + (lane >> 4) * 4 + r) * D_ + h * HD_ + (lane & 15);
#pragma unroll
    for (int n = 0; n < 4; ++n)
      O[ro + n * 16] = (bf16_t)(ctx[n][r] * inv);
  }
}

// ---------------------------------------------------------------------------
// Kernel 4: out = LayerNorm(a + res) * g + b.  a,res bf16; g,b f32;
// OUT = bf16 (intermediate) or float (final output).
// ---------------------------------------------------------------------------
template <typename OUT>
__global__ __launch_bounds__(256) void add_ln_kernel(
    const bf16_t* __restrict__ a, const bf16_t* __restrict__ res,
    const float* __restrict__ g, const float* __restrict__ be,
    OUT* __restrict__ out) {
  const int t = threadIdx.x;
  const int d0 = t * 4;
  const size_t base = (size_t)blockIdx.x * D_ + d0;
  float x[4];
  float s1 = 0.f, s2 = 0.f;
#pragma unroll
  for (int e = 0; e < 4; ++e) {
    x[e] = (float)a[base + e] + (float)res[base + e];
    s1 += x[e];
    s2 += x[e] * x[e];
  }
#pragma unroll
  for (int o = 32; o > 0; o >>= 1) {
    s1 += __shfl_down(s1, o);
    s2 += __shfl_down(s2, o);
  }
  __shared__ float red[8];
  const int lane = t & 63, wid = t >> 6;
  if (lane == 0) { red[wid] = s1; red[4 + wid] = s2; }
  __syncthreads();
  if (t == 0) {
    float t1 = red[0] + red[1] + red[2] + red[3];
    float t2 = red[4] + red[5] + red[6] + red[7];
    float mu = t1 * (1.f / D_);
    float var = t2 * (1.f / D_) - mu * mu;
    red[0] = mu;
    red[1] = rsqrtf(var + 1e-5f);
  }
  __syncthreads();
  const float mu = red[0], rstd = red[1];
#pragma unroll
  for (int e = 0; e < 4; ++e)
    out[base + e] = (OUT)((x[e] - mu) * rstd * g[d0 + e] + be[d0 + e]);
}

// ---------------------------------------------------------------------------
extern "C" void kernel_launch(void* const* d_in, const int* in_sizes, int n_in,
                              void* d_out, int out_size, void* d_ws, size_t ws_size,
                              hipStream_t stream) {
  const float* key   = (const float*)d_in[0];
  const float* value = (const float*)d_in[1];
  const float* query = (const float*)d_in[2];
  const float* Wq = (const float*)d_in[3];
  const float* Wk = (const float*)d_in[4];
  const float* Wv = (const float*)d_in[5];
  const float* Wo = (const float*)d_in[6];
  const float* W1 = (const float*)d_in[7];
  const float* b1 = (const float*)d_in[8];
  const float* W2 = (const float*)d_in[9];
  const float* b2 = (const float*)d_in[10];
  const float* g1 = (const float*)d_in[11];
  const float* be1 = (const float*)d_in[12];
  const float* g2 = (const float*)d_in[13];
  const float* be2 = (const float*)d_in[14];
  float* out = (float*)d_out;

  bf16_t* ws = (bf16_t*)d_ws;
  const size_t NB = (size_t)B_ * S_ * D_;  // 4 Mi elems, 8 MiB bf16
  bf16_t* qpe = ws + 0 * NB;
  bf16_t* kpe = ws + 1 * NB;
  bf16_t* vpe = ws + 2 * NB;
  bf16_t* Qp  = ws + 3 * NB;
  bf16_t* Kp  = ws + 4 * NB;
  bf16_t* Vp  = ws + 5 * NB;
  // liveness-based reuse
  bf16_t* ctx = kpe;  // kpe dead after projections
  bf16_t* ao  = vpe;  // vpe dead after projections
  bf16_t* x1  = Qp;   // Qp dead after attention
  bf16_t* hh  = Kp;   // Kp dead after attention
  bf16_t* ff  = Vp;   // Vp dead after attention

  const int M = B_ * S_, N = D_, Kd = D_;
  dim3 ggrid(N / 128, M / 128);  // 8 x 32

  addpe_kernel<<<B_ * S_, 256, 0, stream>>>(query, key, value, qpe, kpe, vpe);

  gemm_bt<0><<<ggrid, 256, 0, stream>>>(qpe, Wq, nullptr, Qp, M, N, Kd);
  gemm_bt<0><<<ggrid, 256, 0, stream>>>(kpe, Wk, nullptr, Kp, M, N, Kd);
  gemm_bt<0><<<ggrid, 256, 0, stream>>>(vpe, Wv, nullptr, Vp, M, N, Kd);

  attn_kernel<<<dim3(S_ / 64, B_ * H_), 256, 0, stream>>>(Qp, Kp, Vp, ctx);

  gemm_bt<0><<<ggrid, 256, 0, stream>>>(ctx, Wo, nullptr, ao, M, N, Kd);
  add_ln_kernel<bf16_t><<<B_ * S_, 256, 0, stream>>>(ao, qpe, g1, be1, x1);

  gemm_bt<2><<<ggrid, 256, 0, stream>>>(x1, W1, b1, hh, M, N, Kd);
  gemm_bt<1><<<ggrid, 256, 0, stream>>>(hh, W2, b2, ff, M, N, Kd);
  add_ln_kernel<float><<<B_ * S_, 256, 0, stream>>>(ff, x1, g2, be2, out);
}

// Round 4
// 284.090 us; speedup vs baseline: 1.5557x; 1.5557x over previous
//
#include <hip/hip_runtime.h>
#include <hip/hip_bf16.h>
#include <math.h>

// ---------------------------------------------------------------------------
// TransformerLayer: B=2 S=2048 D=1024 H=16 HD=64. I/O f32, internals bf16.
// Round 4: pipelined 128x64 GEMMs (2-phase dbuf, gload_lds A, reg-staged f32
// weights), batched QKV GEMM (grid.z=3, V written transposed), attention with
// KVBLK=64, swizzled K/Vt LDS staging (conflict-free b128 reads), padded P.
// ---------------------------------------------------------------------------

#define B_ 2
#define S_ 2048
#define D_ 1024
#define H_ 16
#define HD_ 64

typedef __bf16 bf16_t;
typedef __bf16 bf16x8 __attribute__((ext_vector_type(8)));
typedef __bf16 bf16x4v __attribute__((ext_vector_type(4)));
typedef float f32x4 __attribute__((ext_vector_type(4)));

__device__ __forceinline__ f32x4 mfma16(bf16x8 a, bf16x8 b, f32x4 c) {
  return __builtin_amdgcn_mfma_f32_16x16x32_bf16(a, b, c, 0, 0, 0);
}

// global -> LDS direct copy, 16B/lane. LDS dest: wave-uniform base + lane*16.
__device__ __forceinline__ void gload_lds16(const bf16_t* g, bf16_t* l) {
  __builtin_amdgcn_global_load_lds((const __attribute__((address_space(1))) void*)g,
                                   (__attribute__((address_space(3))) void*)l,
                                   16, 0, 0);
}

// ---------------------------------------------------------------------------
// Kernel 1: positional encoding + add; f32 in -> bf16 out (q,k,v one pass).
// ---------------------------------------------------------------------------
__global__ __launch_bounds__(256) void addpe_kernel(
    const float* __restrict__ q, const float* __restrict__ k,
    const float* __restrict__ v,
    bf16_t* __restrict__ qo, bf16_t* __restrict__ ko, bf16_t* __restrict__ vo) {
  const int row = blockIdx.x;            // b*S + s
  const int s = row & (S_ - 1);
  const int d0 = threadIdx.x * 4;
  const size_t base = (size_t)row * D_ + d0;
  float pe[4];
#pragma unroll
  for (int p = 0; p < 2; ++p) {
    float div = __expf((float)(d0 + 2 * p) * -0.008994473019508f);
    float ang = (float)s * div;
    pe[2 * p]     = sinf(ang);
    pe[2 * p + 1] = cosf(ang);
  }
  float4 qv = *(const float4*)&q[base];
  float4 kv = *(const float4*)&k[base];
  float4 vv = *(const float4*)&v[base];
  bf16x4v qr, kr, vr;
  qr[0] = (bf16_t)(qv.x + pe[0]); qr[1] = (bf16_t)(qv.y + pe[1]);
  qr[2] = (bf16_t)(qv.z + pe[2]); qr[3] = (bf16_t)(qv.w + pe[3]);
  kr[0] = (bf16_t)(kv.x + pe[0]); kr[1] = (bf16_t)(kv.y + pe[1]);
  kr[2] = (bf16_t)(kv.z + pe[2]); kr[3] = (bf16_t)(kv.w + pe[3]);
  vr[0] = (bf16_t)(vv.x + pe[0]); vr[1] = (bf16_t)(vv.y + pe[1]);
  vr[2] = (bf16_t)(vv.z + pe[2]); vr[3] = (bf16_t)(vv.w + pe[3]);
  *(bf16x4v*)&qo[base] = qr;
  *(bf16x4v*)&ko[base] = kr;
  *(bf16x4v*)&vo[base] = vr;
}

// ---------------------------------------------------------------------------
// Kernel 2: NT GEMM C[M=4096,N=1024] = A[M,1024] x W[1024,1024]^T, bf16 MFMA.
// Tile 128x64, BK=32, 4 waves (2x2, each 64x32). 2-phase dbuf, 1 barrier/iter.
// A: bf16 via global_load_lds. W: f32 via reg-stage + cvt (T14 split).
// MODE: 0 plain, 1 +bias, 2 +bias+relu, 3 QKV batched (z: 0=Q,1=K,2=V^T out)
// ---------------------------------------------------------------------------
template <int MODE>
__global__ __launch_bounds__(256) void gemm2p(
    const bf16_t* __restrict__ a0p, const bf16_t* __restrict__ a1p,
    const bf16_t* __restrict__ a2p,
    const float* __restrict__ w0p, const float* __restrict__ w1p,
    const float* __restrict__ w2p,
    const float* __restrict__ bias,
    bf16_t* __restrict__ o0, bf16_t* __restrict__ o1, bf16_t* __restrict__ o2) {
  constexpr int Kd = 1024, NT = Kd / 32;
  __shared__ alignas(16) bf16_t As[2][128 * 32];
  __shared__ alignas(16) bf16_t Bs[2][64 * 32];
  const int t = threadIdx.x, lane = t & 63, wid = t >> 6;
  const int m0 = blockIdx.y * 128, n0 = blockIdx.x * 64;

  const bf16_t* A = a0p;
  const float* Wf = w0p;
  if (MODE == 3) {
    if (blockIdx.z == 1) { A = a1p; Wf = w1p; }
    else if (blockIdx.z == 2) { A = a2p; Wf = w2p; }
  }

  // A staging: wave w writes LDS elems [w*512 + l*8) (rows w*16 + l/4) per chunk
  const bf16_t* Asrc0 = A + (size_t)(m0 + wid * 16 + (lane >> 2)) * Kd + (lane & 3) * 8;
  const bf16_t* Asrc1 = Asrc0 + (size_t)64 * Kd;
  // W staging: thread t: row n0 + t/4, col (t%4)*8 (f32)
  const float* Wsrc = Wf + (size_t)(n0 + (t >> 2)) * Kd + (t & 3) * 8;

  const f32x4 zero = {0.f, 0.f, 0.f, 0.f};
  f32x4 acc[4][2];
#pragma unroll
  for (int m = 0; m < 4; ++m) { acc[m][0] = zero; acc[m][1] = zero; }

  // prologue: stage tile 0 into buf 0
  gload_lds16(Asrc0, &As[0][wid * 512]);
  gload_lds16(Asrc1, &As[0][2048 + wid * 512]);
  {
    float4 w0 = *(const float4*)(Wsrc);
    float4 w1 = *(const float4*)(Wsrc + 4);
    bf16x8 wb;
    wb[0] = (bf16_t)w0.x; wb[1] = (bf16_t)w0.y; wb[2] = (bf16_t)w0.z; wb[3] = (bf16_t)w0.w;
    wb[4] = (bf16_t)w1.x; wb[5] = (bf16_t)w1.y; wb[6] = (bf16_t)w1.z; wb[7] = (bf16_t)w1.w;
    *(bf16x8*)&Bs[0][t * 8] = wb;
  }

  const int wr = wid >> 1, wc = wid & 1;
  for (int kt = 0; kt < NT; ++kt) {
    __syncthreads();                       // tile kt resident (vm+lgkm drained)
    const int cur = kt & 1, nxt = cur ^ 1;
    float4 w0, w1;
    if (kt + 1 < NT) {
      const int k0 = (kt + 1) * 32;
      gload_lds16(Asrc0 + k0, &As[nxt][wid * 512]);
      gload_lds16(Asrc1 + k0, &As[nxt][2048 + wid * 512]);
      w0 = *(const float4*)(Wsrc + k0);    // issue now, consume after MFMAs
      w1 = *(const float4*)(Wsrc + k0 + 4);
    }
    bf16x8 af[4], bfr[2];
#pragma unroll
    for (int m = 0; m < 4; ++m)
      af[m] = *(const bf16x8*)&As[cur][(wr * 64 + m * 16 + (lane & 15)) * 32 + (lane >> 4) * 8];
#pragma unroll
    for (int n = 0; n < 2; ++n)
      bfr[n] = *(const bf16x8*)&Bs[cur][(wc * 32 + n * 16 + (lane & 15)) * 32 + (lane >> 4) * 8];
#pragma unroll
    for (int m = 0; m < 4; ++m)
#pragma unroll
      for (int n = 0; n < 2; ++n)
        acc[m][n] = mfma16(af[m], bfr[n], acc[m][n]);
    if (kt + 1 < NT) {                     // T14: cvt+write after compute
      bf16x8 wb;
      wb[0] = (bf16_t)w0.x; wb[1] = (bf16_t)w0.y; wb[2] = (bf16_t)w0.z; wb[3] = (bf16_t)w0.w;
      wb[4] = (bf16_t)w1.x; wb[5] = (bf16_t)w1.y; wb[6] = (bf16_t)w1.z; wb[7] = (bf16_t)w1.w;
      *(bf16x8*)&Bs[nxt][t * 8] = wb;
    }
  }

  // epilogue: D frag: col = lane&15, row = (lane>>4)*4 + r
  const int rbase = m0 + wr * 64 + (lane >> 4) * 4;
  const int cbase = n0 + wc * 32 + (lane & 15);
  if (MODE == 3 && blockIdx.z == 2) {
    // V^T: o2[b][d][s] = acc at (row=b*S+s, col=d)
#pragma unroll
    for (int n = 0; n < 2; ++n) {
      const int col = cbase + n * 16;
#pragma unroll
      for (int m = 0; m < 4; ++m)
#pragma unroll
        for (int r = 0; r < 4; ++r) {
          const int row = rbase + m * 16 + r;
          const int bb = row >> 11, ss = row & (S_ - 1);
          o2[(size_t)bb * D_ * S_ + (size_t)col * S_ + ss] = (bf16_t)acc[m][n][r];
        }
    }
  } else {
    bf16_t* C = o0;
    if (MODE == 3 && blockIdx.z == 1) C = o1;
#pragma unroll
    for (int n = 0; n < 2; ++n) {
      const int col = cbase + n * 16;
      float bv = (MODE == 1 || MODE == 2) ? bias[col] : 0.f;
#pragma unroll
      for (int m = 0; m < 4; ++m)
#pragma unroll
        for (int r = 0; r < 4; ++r) {
          float vv = acc[m][n][r] + bv;
          if (MODE == 2) vv = fmaxf(vv, 0.f);
          C[(size_t)(rbase + m * 16 + r) * D_ + col] = (bf16_t)vv;
        }
    }
  }
}

// ---------------------------------------------------------------------------
// Kernel 3: flash attention. grid (S/64, B*H), 4 waves x 16 q-rows.
// KVBLK=64. K (from Kp[s][d]) and V^T (from Vt[d][s]) staged to LDS via
// gload_lds with pre-swizzled global source (slot ^= row&7); reads are
// swizzled ds_read_b128 -> conflict-free. 2-phase dbuf, 1 barrier/iter.
// P via padded per-wave LDS (stride 72), same-wave ordering (no barrier).
// ---------------------------------------------------------------------------
__global__ __launch_bounds__(256) void attn_kernel(
    const bf16_t* __restrict__ Q, const bf16_t* __restrict__ K,
    const bf16_t* __restrict__ Vt, bf16_t* __restrict__ O) {
  constexpr int NT = S_ / 64;
  __shared__ alignas(16) bf16_t Ks[2][64 * 64];
  __shared__ alignas(16) bf16_t Vs[2][64 * 64];
  __shared__ alignas(16) bf16_t Ps[4 * 16 * 72];
  const int t = threadIdx.x, lane = t & 63, wid = t >> 6;
  const int b = blockIdx.y >> 4, h = blockIdx.y & 15;
  const int q0 = blockIdx.x * 64 + wid * 16;
  const int g = lane >> 4, c16 = lane & 15;

  // Q frags (A-op: row=c16=q, k=d=g*8+j), pre-scaled by 1/sqrt(64) (exact)
  const size_t rowQ = (size_t)(b * S_ + q0 + c16) * D_ + h * HD_ + g * 8;
  bf16x8 qa0 = *(const bf16x8*)&Q[rowQ];
  bf16x8 qa1 = *(const bf16x8*)&Q[rowQ + 32];
#pragma unroll
  for (int j = 0; j < 8; ++j) {
    qa0[j] = (bf16_t)((float)qa0[j] * 0.125f);
    qa1[j] = (bf16_t)((float)qa1[j] * 0.125f);
  }

  const f32x4 zero = {0.f, 0.f, 0.f, 0.f};
  f32x4 ctx[4] = {zero, zero, zero, zero};
  float mrow[4] = {-1e30f, -1e30f, -1e30f, -1e30f};
  float lrow[4] = {0.f, 0.f, 0.f, 0.f};

  // staging: wave w, chunk c covers tile-rows c*32 + w*8 + (lane>>3);
  // phys slot (lane&7) holds logical slot (lane&7)^((lane>>3)&7)  [row&7]
  const int trow = wid * 8 + (lane >> 3);
  const int lslot = ((lane & 7) ^ ((lane >> 3) & 7)) * 8;
  const bf16_t* Ksrc0 = K + (size_t)(b * S_ + trow) * D_ + h * HD_ + lslot;
  const bf16_t* Ksrc1 = K + (size_t)(b * S_ + 32 + trow) * D_ + h * HD_ + lslot;
  const bf16_t* Vsrc0 = Vt + (size_t)b * D_ * S_ + (size_t)(h * HD_ + trow) * S_ + lslot;
  const bf16_t* Vsrc1 = Vt + (size_t)b * D_ * S_ + (size_t)(h * HD_ + 32 + trow) * S_ + lslot;

  // prologue: stage tile 0
  gload_lds16(Ksrc0, &Ks[0][wid * 512]);
  gload_lds16(Ksrc1, &Ks[0][2048 + wid * 512]);
  gload_lds16(Vsrc0, &Vs[0][wid * 512]);
  gload_lds16(Vsrc1, &Vs[0][2048 + wid * 512]);

  for (int kt = 0; kt < NT; ++kt) {
    __syncthreads();                       // tile kt resident
    const int cur = kt & 1, nxt = cur ^ 1;
    if (kt + 1 < NT) {
      const size_t ko = (size_t)(kt + 1) * 64 * D_;  // K advances by rows
      gload_lds16(Ksrc0 + ko, &Ks[nxt][wid * 512]);
      gload_lds16(Ksrc1 + ko, &Ks[nxt][2048 + wid * 512]);
      const size_t vo = (size_t)(kt + 1) * 64;       // Vt advances by cols
      gload_lds16(Vsrc0 + vo, &Vs[nxt][wid * 512]);
      gload_lds16(Vsrc1 + vo, &Vs[nxt][2048 + wid * 512]);
    }

    // QK^T: 4 key-frags x 2 d-halves. kb row = key, slot = dh*4+g (swizzled)
    f32x4 sf[4];
#pragma unroll
    for (int kc = 0; kc < 4; ++kc) {
      const int krow = kc * 16 + c16;
      const int p0 = ((0 * 4 + g) ^ (krow & 7)) * 8;
      const int p1 = ((1 * 4 + g) ^ (krow & 7)) * 8;
      bf16x8 kb0 = *(const bf16x8*)&Ks[cur][krow * 64 + p0];
      bf16x8 kb1 = *(const bf16x8*)&Ks[cur][krow * 64 + p1];
      f32x4 z = zero;
      z = mfma16(qa0, kb0, z);
      z = mfma16(qa1, kb1, z);
      sf[kc] = z;
    }

    // online softmax: group g owns q-rows g*4+r; 16 lanes hold 16 keys/frag
#pragma unroll
    for (int r = 0; r < 4; ++r) {
      float s0 = sf[0][r], s1 = sf[1][r], s2 = sf[2][r], s3 = sf[3][r];
      float mx = fmaxf(fmaxf(s0, s1), fmaxf(s2, s3));
#pragma unroll
      for (int o = 1; o < 16; o <<= 1) mx = fmaxf(mx, __shfl_xor(mx, o));
      float mnew = fmaxf(mrow[r], mx);
      float scl = __expf(mrow[r] - mnew);
      float p0 = __expf(s0 - mnew), p1 = __expf(s1 - mnew);
      float p2 = __expf(s2 - mnew), p3 = __expf(s3 - mnew);
      float rs = (p0 + p1) + (p2 + p3);
#pragma unroll
      for (int o = 1; o < 16; o <<= 1) rs += __shfl_xor(rs, o);
      lrow[r] = lrow[r] * scl + rs;
      mrow[r] = mnew;
#pragma unroll
      for (int n = 0; n < 4; ++n) ctx[n][r] *= scl;
      bf16_t* pr = &Ps[wid * 1152 + (g * 4 + r) * 72];
      pr[0 * 16 + c16] = (bf16_t)p0;
      pr[1 * 16 + c16] = (bf16_t)p1;
      pr[2 * 16 + c16] = (bf16_t)p2;
      pr[3 * 16 + c16] = (bf16_t)p3;
    }

    // PV: A = P[q][k] (q=c16, k=ks*32+g*8+j), B = V^T frag (d=n*16+c16)
#pragma unroll
    for (int ks = 0; ks < 2; ++ks) {
      bf16x8 ap = *(const bf16x8*)&Ps[wid * 1152 + c16 * 72 + ks * 32 + g * 8];
#pragma unroll
      for (int n = 0; n < 4; ++n) {
        const int vrow = n * 16 + c16;
        const int ph = ((ks * 4 + g) ^ (vrow & 7)) * 8;
        bf16x8 vb = *(const bf16x8*)&Vs[cur][vrow * 64 + ph];
        ctx[n] = mfma16(ap, vb, ctx[n]);
      }
    }
  }

  // write (D-frag: row=g*4+r, col=n*16+c16)
#pragma unroll
  for (int r = 0; r < 4; ++r) {
    float inv = 1.f / lrow[r];
    const size_t ro = (size_t)(b * S_ + q0 + g * 4 + r) * D_ + h * HD_ + c16;
#pragma unroll
    for (int n = 0; n < 4; ++n)
      O[ro + n * 16] = (bf16_t)(ctx[n][r] * inv);
  }
}

// ---------------------------------------------------------------------------
// Kernel 4: out = LayerNorm(a + res) * g + b.  a,res bf16; g,b f32.
// ---------------------------------------------------------------------------
template <typename OUT>
__global__ __launch_bounds__(256) void add_ln_kernel(
    const bf16_t* __restrict__ a, const bf16_t* __restrict__ res,
    const float* __restrict__ g, const float* __restrict__ be,
    OUT* __restrict__ out) {
  const int t = threadIdx.x;
  const int d0 = t * 4;
  const size_t base = (size_t)blockIdx.x * D_ + d0;
  float x[4];
  float s1 = 0.f, s2 = 0.f;
#pragma unroll
  for (int e = 0; e < 4; ++e) {
    x[e] = (float)a[base + e] + (float)res[base + e];
    s1 += x[e];
    s2 += x[e] * x[e];
  }
#pragma unroll
  for (int o = 32; o > 0; o >>= 1) {
    s1 += __shfl_down(s1, o);
    s2 += __shfl_down(s2, o);
  }
  __shared__ float red[8];
  const int lane = t & 63, wid = t >> 6;
  if (lane == 0) { red[wid] = s1; red[4 + wid] = s2; }
  __syncthreads();
  if (t == 0) {
    float t1 = red[0] + red[1] + red[2] + red[3];
    float t2 = red[4] + red[5] + red[6] + red[7];
    float mu = t1 * (1.f / D_);
    float var = t2 * (1.f / D_) - mu * mu;
    red[0] = mu;
    red[1] = rsqrtf(var + 1e-5f);
  }
  __syncthreads();
  const float mu = red[0], rstd = red[1];
#pragma unroll
  for (int e = 0; e < 4; ++e)
    out[base + e] = (OUT)((x[e] - mu) * rstd * g[d0 + e] + be[d0 + e]);
}

// ---------------------------------------------------------------------------
extern "C" void kernel_launch(void* const* d_in, const int* in_sizes, int n_in,
                              void* d_out, int out_size, void* d_ws, size_t ws_size,
                              hipStream_t stream) {
  const float* key   = (const float*)d_in[0];
  const float* value = (const float*)d_in[1];
  const float* query = (const float*)d_in[2];
  const float* Wq = (const float*)d_in[3];
  const float* Wk = (const float*)d_in[4];
  const float* Wv = (const float*)d_in[5];
  const float* Wo = (const float*)d_in[6];
  const float* W1 = (const float*)d_in[7];
  const float* b1 = (const float*)d_in[8];
  const float* W2 = (const float*)d_in[9];
  const float* b2 = (const float*)d_in[10];
  const float* g1 = (const float*)d_in[11];
  const float* be1 = (const float*)d_in[12];
  const float* g2 = (const float*)d_in[13];
  const float* be2 = (const float*)d_in[14];
  float* out = (float*)d_out;

  bf16_t* ws = (bf16_t*)d_ws;
  const size_t NB = (size_t)B_ * S_ * D_;  // 4 Mi elems
  bf16_t* qpe = ws + 0 * NB;
  bf16_t* kpe = ws + 1 * NB;
  bf16_t* vpe = ws + 2 * NB;
  bf16_t* Qp  = ws + 3 * NB;
  bf16_t* Kp  = ws + 4 * NB;
  bf16_t* Vt  = ws + 5 * NB;   // [B][D][S] transposed V projection
  bf16_t* ctx = kpe;  // dead after QKV gemm
  bf16_t* ao  = vpe;  // dead after QKV gemm
  bf16_t* x1  = Qp;   // dead after attention
  bf16_t* hh  = Kp;   // dead after attention
  bf16_t* ff  = Vt;   // dead after attention

  dim3 ggrid(D_ / 64, (B_ * S_) / 128);        // 16 x 32

  addpe_kernel<<<B_ * S_, 256, 0, stream>>>(query, key, value, qpe, kpe, vpe);

  gemm2p<3><<<dim3(D_ / 64, (B_ * S_) / 128, 3), 256, 0, stream>>>(
      qpe, kpe, vpe, Wq, Wk, Wv, nullptr, Qp, Kp, Vt);

  attn_kernel<<<dim3(S_ / 64, B_ * H_), 256, 0, stream>>>(Qp, Kp, Vt, ctx);

  gemm2p<0><<<ggrid, 256, 0, stream>>>(ctx, nullptr, nullptr, Wo, nullptr, nullptr,
                                       nullptr, ao, nullptr, nullptr);
  add_ln_kernel<bf16_t><<<B_ * S_, 256, 0, stream>>>(ao, qpe, g1, be1, x1);

  gemm2p<2><<<ggrid, 256, 0, stream>>>(x1, nullptr, nullptr, W1, nullptr, nullptr,
                                       b1, hh, nullptr, nullptr);
  gemm2p<1><<<ggrid, 256, 0, stream>>>(hh, nullptr, nullptr, W2, nullptr, nullptr,
                                       b2, ff, nullptr, nullptr);
  add_ln_kernel<float><<<B_ * S_, 256, 0, stream>>>(ff, x1, g2, be2, out);
}

// Round 5
// 254.991 us; speedup vs baseline: 1.7332x; 1.1141x over previous
//
#include <hip/hip_runtime.h>
#include <hip/hip_bf16.h>
#include <math.h>

// ---------------------------------------------------------------------------
// TransformerLayer: B=2 S=2048 D=1024 H=16 HD=64. I/O f32, internals bf16.
// Round 5: (1) weights pre-converted to bf16 once (stored in d_out scratch),
// GEMM inner loop all-global_load_lds; (2) attention defer-max softmax
// (skip max-reduce + ctx rescale when running max holds, THR=8).
// ---------------------------------------------------------------------------

#define B_ 2
#define S_ 2048
#define D_ 1024
#define H_ 16
#define HD_ 64

typedef __bf16 bf16_t;
typedef __bf16 bf16x8 __attribute__((ext_vector_type(8)));
typedef __bf16 bf16x4v __attribute__((ext_vector_type(4)));
typedef float f32x4 __attribute__((ext_vector_type(4)));

__device__ __forceinline__ f32x4 mfma16(bf16x8 a, bf16x8 b, f32x4 c) {
  return __builtin_amdgcn_mfma_f32_16x16x32_bf16(a, b, c, 0, 0, 0);
}

// global -> LDS direct copy, 16B/lane. LDS dest: wave-uniform base + lane*16.
__device__ __forceinline__ void gload_lds16(const bf16_t* g, bf16_t* l) {
  __builtin_amdgcn_global_load_lds((const __attribute__((address_space(1))) void*)g,
                                   (__attribute__((address_space(3))) void*)l,
                                   16, 0, 0);
}

// ---------------------------------------------------------------------------
// Kernel 0: convert 6 f32 weight matrices (D x D) to bf16, contiguous in dst.
// grid (D*D/1024, 6), 256 threads x 4 elems.
// ---------------------------------------------------------------------------
__global__ __launch_bounds__(256) void cvtw_kernel(
    const float* __restrict__ w0, const float* __restrict__ w1,
    const float* __restrict__ w2, const float* __restrict__ w3,
    const float* __restrict__ w4, const float* __restrict__ w5,
    bf16_t* __restrict__ dst) {
  const int wsel = blockIdx.y;
  const float* src = wsel == 0 ? w0 : wsel == 1 ? w1 : wsel == 2 ? w2
                   : wsel == 3 ? w3 : wsel == 4 ? w4 : w5;
  const size_t off = (size_t)blockIdx.x * 1024 + threadIdx.x * 4;
  float4 v = *(const float4*)(src + off);
  bf16x4v r;
  r[0] = (bf16_t)v.x; r[1] = (bf16_t)v.y; r[2] = (bf16_t)v.z; r[3] = (bf16_t)v.w;
  *(bf16x4v*)(dst + (size_t)wsel * (D_ * D_) + off) = r;
}

// ---------------------------------------------------------------------------
// Kernel 1: positional encoding + add; f32 in -> bf16 out (q,k,v one pass).
// ---------------------------------------------------------------------------
__global__ __launch_bounds__(256) void addpe_kernel(
    const float* __restrict__ q, const float* __restrict__ k,
    const float* __restrict__ v,
    bf16_t* __restrict__ qo, bf16_t* __restrict__ ko, bf16_t* __restrict__ vo) {
  const int row = blockIdx.x;            // b*S + s
  const int s = row & (S_ - 1);
  const int d0 = threadIdx.x * 4;
  const size_t base = (size_t)row * D_ + d0;
  float pe[4];
#pragma unroll
  for (int p = 0; p < 2; ++p) {
    float div = __expf((float)(d0 + 2 * p) * -0.008994473019508f);
    float ang = (float)s * div;
    pe[2 * p]     = sinf(ang);
    pe[2 * p + 1] = cosf(ang);
  }
  float4 qv = *(const float4*)&q[base];
  float4 kv = *(const float4*)&k[base];
  float4 vv = *(const float4*)&v[base];
  bf16x4v qr, kr, vr;
  qr[0] = (bf16_t)(qv.x + pe[0]); qr[1] = (bf16_t)(qv.y + pe[1]);
  qr[2] = (bf16_t)(qv.z + pe[2]); qr[3] = (bf16_t)(qv.w + pe[3]);
  kr[0] = (bf16_t)(kv.x + pe[0]); kr[1] = (bf16_t)(kv.y + pe[1]);
  kr[2] = (bf16_t)(kv.z + pe[2]); kr[3] = (bf16_t)(kv.w + pe[3]);
  vr[0] = (bf16_t)(vv.x + pe[0]); vr[1] = (bf16_t)(vv.y + pe[1]);
  vr[2] = (bf16_t)(vv.z + pe[2]); vr[3] = (bf16_t)(vv.w + pe[3]);
  *(bf16x4v*)&qo[base] = qr;
  *(bf16x4v*)&ko[base] = kr;
  *(bf16x4v*)&vo[base] = vr;
}

// ---------------------------------------------------------------------------
// Kernel 2: NT GEMM C[M=4096,N=1024] = A[M,1024] x W[1024,1024]^T, all bf16.
// Tile 128x64, BK=32, 4 waves (2x2, each 64x32). 2-phase dbuf, 1 barrier/iter,
// A and W both staged via global_load_lds (3 gloads/wave/iter).
// MODE: 0 plain, 1 +bias, 2 +bias+relu, 3 QKV batched (z: 0=Q,1=K,2=V^T out)
// ---------------------------------------------------------------------------
template <int MODE>
__global__ __launch_bounds__(256) void gemm2p(
    const bf16_t* __restrict__ a0p, const bf16_t* __restrict__ a1p,
    const bf16_t* __restrict__ a2p,
    const bf16_t* __restrict__ w0p, const bf16_t* __restrict__ w1p,
    const bf16_t* __restrict__ w2p,
    const float* __restrict__ bias,
    bf16_t* __restrict__ o0, bf16_t* __restrict__ o1, bf16_t* __restrict__ o2) {
  constexpr int Kd = 1024, NT = Kd / 32;
  __shared__ alignas(16) bf16_t As[2][128 * 32];
  __shared__ alignas(16) bf16_t Bs[2][64 * 32];
  const int t = threadIdx.x, lane = t & 63, wid = t >> 6;
  const int m0 = blockIdx.y * 128, n0 = blockIdx.x * 64;

  const bf16_t* A = a0p;
  const bf16_t* Wb = w0p;
  if (MODE == 3) {
    if (blockIdx.z == 1) { A = a1p; Wb = w1p; }
    else if (blockIdx.z == 2) { A = a2p; Wb = w2p; }
  }

  // staging: wave chunk = 16 rows x 32 cols; lane l -> row +l/4, col (l%4)*8
  const bf16_t* Asrc0 = A + (size_t)(m0 + wid * 16 + (lane >> 2)) * Kd + (lane & 3) * 8;
  const bf16_t* Asrc1 = Asrc0 + (size_t)64 * Kd;
  const bf16_t* Wsrc = Wb + (size_t)(n0 + wid * 16 + (lane >> 2)) * Kd + (lane & 3) * 8;

  const f32x4 zero = {0.f, 0.f, 0.f, 0.f};
  f32x4 acc[4][2];
#pragma unroll
  for (int m = 0; m < 4; ++m) { acc[m][0] = zero; acc[m][1] = zero; }

  // prologue: stage tile 0 into buf 0
  gload_lds16(Asrc0, &As[0][wid * 512]);
  gload_lds16(Asrc1, &As[0][2048 + wid * 512]);
  gload_lds16(Wsrc,  &Bs[0][wid * 512]);

  const int wr = wid >> 1, wc = wid & 1;
  for (int kt = 0; kt < NT; ++kt) {
    __syncthreads();                       // tile kt resident (vm drained)
    const int cur = kt & 1, nxt = cur ^ 1;
    if (kt + 1 < NT) {
      const int k0 = (kt + 1) * 32;
      gload_lds16(Asrc0 + k0, &As[nxt][wid * 512]);
      gload_lds16(Asrc1 + k0, &As[nxt][2048 + wid * 512]);
      gload_lds16(Wsrc + k0,  &Bs[nxt][wid * 512]);
    }
    bf16x8 af[4], bfr[2];
#pragma unroll
    for (int m = 0; m < 4; ++m)
      af[m] = *(const bf16x8*)&As[cur][(wr * 64 + m * 16 + (lane & 15)) * 32 + (lane >> 4) * 8];
#pragma unroll
    for (int n = 0; n < 2; ++n)
      bfr[n] = *(const bf16x8*)&Bs[cur][(wc * 32 + n * 16 + (lane & 15)) * 32 + (lane >> 4) * 8];
#pragma unroll
    for (int m = 0; m < 4; ++m)
#pragma unroll
      for (int n = 0; n < 2; ++n)
        acc[m][n] = mfma16(af[m], bfr[n], acc[m][n]);
  }

  // epilogue: D frag: col = lane&15, row = (lane>>4)*4 + r
  const int rbase = m0 + wr * 64 + (lane >> 4) * 4;
  const int cbase = n0 + wc * 32 + (lane & 15);
  if (MODE == 3 && blockIdx.z == 2) {
    // V^T: o2[b][d][s] = acc at (row=b*S+s, col=d)
#pragma unroll
    for (int n = 0; n < 2; ++n) {
      const int col = cbase + n * 16;
#pragma unroll
      for (int m = 0; m < 4; ++m)
#pragma unroll
        for (int r = 0; r < 4; ++r) {
          const int row = rbase + m * 16 + r;
          const int bb = row >> 11, ss = row & (S_ - 1);
          o2[(size_t)bb * D_ * S_ + (size_t)col * S_ + ss] = (bf16_t)acc[m][n][r];
        }
    }
  } else {
    bf16_t* C = o0;
    if (MODE == 3 && blockIdx.z == 1) C = o1;
#pragma unroll
    for (int n = 0; n < 2; ++n) {
      const int col = cbase + n * 16;
      float bv = (MODE == 1 || MODE == 2) ? bias[col] : 0.f;
#pragma unroll
      for (int m = 0; m < 4; ++m)
#pragma unroll
        for (int r = 0; r < 4; ++r) {
          float vv = acc[m][n][r] + bv;
          if (MODE == 2) vv = fmaxf(vv, 0.f);
          C[(size_t)(rbase + m * 16 + r) * D_ + col] = (bf16_t)vv;
        }
    }
  }
}

// ---------------------------------------------------------------------------
// Kernel 3: flash attention. grid (S/64, B*H), 4 waves x 16 q-rows, KVBLK=64.
// Swizzled gload_lds K/Vt staging (conflict-free b128 reads), 2-phase dbuf.
// Defer-max online softmax (THR=8): skip max-reduce + rescale when the
// running max holds (wave-uniform __any decision from unreduced maxima).
// ---------------------------------------------------------------------------
__global__ __launch_bounds__(256) void attn_kernel(
    const bf16_t* __restrict__ Q, const bf16_t* __restrict__ K,
    const bf16_t* __restrict__ Vt, bf16_t* __restrict__ O) {
  constexpr int NT = S_ / 64;
  __shared__ alignas(16) bf16_t Ks[2][64 * 64];
  __shared__ alignas(16) bf16_t Vs[2][64 * 64];
  __shared__ alignas(16) bf16_t Ps[4 * 16 * 72];
  const int t = threadIdx.x, lane = t & 63, wid = t >> 6;
  const int b = blockIdx.y >> 4, h = blockIdx.y & 15;
  const int q0 = blockIdx.x * 64 + wid * 16;
  const int g = lane >> 4, c16 = lane & 15;

  // Q frags (A-op: row=c16=q, k=d=g*8+j), pre-scaled by 1/sqrt(64) (exact)
  const size_t rowQ = (size_t)(b * S_ + q0 + c16) * D_ + h * HD_ + g * 8;
  bf16x8 qa0 = *(const bf16x8*)&Q[rowQ];
  bf16x8 qa1 = *(const bf16x8*)&Q[rowQ + 32];
#pragma unroll
  for (int j = 0; j < 8; ++j) {
    qa0[j] = (bf16_t)((float)qa0[j] * 0.125f);
    qa1[j] = (bf16_t)((float)qa1[j] * 0.125f);
  }

  const f32x4 zero = {0.f, 0.f, 0.f, 0.f};
  f32x4 ctx[4] = {zero, zero, zero, zero};
  float mrow[4] = {-1e30f, -1e30f, -1e30f, -1e30f};
  float lrow[4] = {0.f, 0.f, 0.f, 0.f};

  // staging: wave w, chunk c covers tile-rows c*32 + w*8 + (lane>>3);
  // phys slot (lane&7) holds logical slot (lane&7)^(row&7)
  const int trow = wid * 8 + (lane >> 3);
  const int lslot = ((lane & 7) ^ ((lane >> 3) & 7)) * 8;
  const bf16_t* Ksrc0 = K + (size_t)(b * S_ + trow) * D_ + h * HD_ + lslot;
  const bf16_t* Ksrc1 = K + (size_t)(b * S_ + 32 + trow) * D_ + h * HD_ + lslot;
  const bf16_t* Vsrc0 = Vt + (size_t)b * D_ * S_ + (size_t)(h * HD_ + trow) * S_ + lslot;
  const bf16_t* Vsrc1 = Vt + (size_t)b * D_ * S_ + (size_t)(h * HD_ + 32 + trow) * S_ + lslot;

  // prologue: stage tile 0
  gload_lds16(Ksrc0, &Ks[0][wid * 512]);
  gload_lds16(Ksrc1, &Ks[0][2048 + wid * 512]);
  gload_lds16(Vsrc0, &Vs[0][wid * 512]);
  gload_lds16(Vsrc1, &Vs[0][2048 + wid * 512]);

  for (int kt = 0; kt < NT; ++kt) {
    __syncthreads();                       // tile kt resident
    const int cur = kt & 1, nxt = cur ^ 1;
    if (kt + 1 < NT) {
      const size_t ko = (size_t)(kt + 1) * 64 * D_;  // K advances by rows
      gload_lds16(Ksrc0 + ko, &Ks[nxt][wid * 512]);
      gload_lds16(Ksrc1 + ko, &Ks[nxt][2048 + wid * 512]);
      const size_t vo = (size_t)(kt + 1) * 64;       // Vt advances by cols
      gload_lds16(Vsrc0 + vo, &Vs[nxt][wid * 512]);
      gload_lds16(Vsrc1 + vo, &Vs[nxt][2048 + wid * 512]);
    }

    // QK^T: 4 key-frags x 2 d-halves. kb row = key, slot = dh*4+g (swizzled)
    f32x4 sf[4];
#pragma unroll
    for (int kc = 0; kc < 4; ++kc) {
      const int krow = kc * 16 + c16;
      const int p0 = ((0 * 4 + g) ^ (krow & 7)) * 8;
      const int p1 = ((1 * 4 + g) ^ (krow & 7)) * 8;
      bf16x8 kb0 = *(const bf16x8*)&Ks[cur][krow * 64 + p0];
      bf16x8 kb1 = *(const bf16x8*)&Ks[cur][krow * 64 + p1];
      f32x4 z = zero;
      z = mfma16(qa0, kb0, z);
      z = mfma16(qa1, kb1, z);
      sf[kc] = z;
    }

    // defer-max decision from UNREDUCED per-lane maxima (wave-uniform)
    float lmx[4];
#pragma unroll
    for (int r = 0; r < 4; ++r)
      lmx[r] = fmaxf(fmaxf(sf[0][r], sf[1][r]), fmaxf(sf[2][r], sf[3][r]));
    const bool needl = (lmx[0] > mrow[0] + 8.f) | (lmx[1] > mrow[1] + 8.f) |
                       (lmx[2] > mrow[2] + 8.f) | (lmx[3] > mrow[3] + 8.f);
    if (__any(needl)) {
#pragma unroll
      for (int r = 0; r < 4; ++r) {
        float mx = lmx[r];
#pragma unroll
        for (int o = 1; o < 16; o <<= 1) mx = fmaxf(mx, __shfl_xor(mx, o));
        float mnew = fmaxf(mrow[r], mx);
        float scl = __expf(mrow[r] - mnew);
        lrow[r] *= scl;
#pragma unroll
        for (int n = 0; n < 4; ++n) ctx[n][r] *= scl;
        mrow[r] = mnew;
      }
    }

    // P = exp(s - mrow) (bounded by e^8), sum-reduce, store to padded LDS
#pragma unroll
    for (int r = 0; r < 4; ++r) {
      float p0 = __expf(sf[0][r] - mrow[r]), p1 = __expf(sf[1][r] - mrow[r]);
      float p2 = __expf(sf[2][r] - mrow[r]), p3 = __expf(sf[3][r] - mrow[r]);
      float rs = (p0 + p1) + (p2 + p3);
#pragma unroll
      for (int o = 1; o < 16; o <<= 1) rs += __shfl_xor(rs, o);
      lrow[r] += rs;
      bf16_t* pr = &Ps[wid * 1152 + (g * 4 + r) * 72];
      pr[0 * 16 + c16] = (bf16_t)p0;
      pr[1 * 16 + c16] = (bf16_t)p1;
      pr[2 * 16 + c16] = (bf16_t)p2;
      pr[3 * 16 + c16] = (bf16_t)p3;
    }

    // PV: A = P[q][k] (q=c16, k=ks*32+g*8+j), B = V^T frag (d=n*16+c16)
#pragma unroll
    for (int ks = 0; ks < 2; ++ks) {
      bf16x8 ap = *(const bf16x8*)&Ps[wid * 1152 + c16 * 72 + ks * 32 + g * 8];
#pragma unroll
      for (int n = 0; n < 4; ++n) {
        const int vrow = n * 16 + c16;
        const int ph = ((ks * 4 + g) ^ (vrow & 7)) * 8;
        bf16x8 vb = *(const bf16x8*)&Vs[cur][vrow * 64 + ph];
        ctx[n] = mfma16(ap, vb, ctx[n]);
      }
    }
  }

  // write (D-frag: row=g*4+r, col=n*16+c16)
#pragma unroll
  for (int r = 0; r < 4; ++r) {
    float inv = 1.f / lrow[r];
    const size_t ro = (size_t)(b * S_ + q0 + g * 4 + r) * D_ + h * HD_ + c16;
#pragma unroll
    for (int n = 0; n < 4; ++n)
      O[ro + n * 16] = (bf16_t)(ctx[n][r] * inv);
  }
}

// ---------------------------------------------------------------------------
// Kernel 4: out = LayerNorm(a + res) * g + b.  a,res bf16; g,b f32.
// ---------------------------------------------------------------------------
template <typename OUT>
__global__ __launch_bounds__(256) void add_ln_kernel(
    const bf16_t* __restrict__ a, const bf16_t* __restrict__ res,
    const float* __restrict__ g, const float* __restrict__ be,
    OUT* __restrict__ out) {
  const int t = threadIdx.x;
  const int d0 = t * 4;
  const size_t base = (size_t)blockIdx.x * D_ + d0;
  float x[4];
  float s1 = 0.f, s2 = 0.f;
#pragma unroll
  for (int e = 0; e < 4; ++e) {
    x[e] = (float)a[base + e] + (float)res[base + e];
    s1 += x[e];
    s2 += x[e] * x[e];
  }
#pragma unroll
  for (int o = 32; o > 0; o >>= 1) {
    s1 += __shfl_down(s1, o);
    s2 += __shfl_down(s2, o);
  }
  __shared__ float red[8];
  const int lane = t & 63, wid = t >> 6;
  if (lane == 0) { red[wid] = s1; red[4 + wid] = s2; }
  __syncthreads();
  if (t == 0) {
    float t1 = red[0] + red[1] + red[2] + red[3];
    float t2 = red[4] + red[5] + red[6] + red[7];
    float mu = t1 * (1.f / D_);
    float var = t2 * (1.f / D_) - mu * mu;
    red[0] = mu;
    red[1] = rsqrtf(var + 1e-5f);
  }
  __syncthreads();
  const float mu = red[0], rstd = red[1];
#pragma unroll
  for (int e = 0; e < 4; ++e)
    out[base + e] = (OUT)((x[e] - mu) * rstd * g[d0 + e] + be[d0 + e]);
}

// ---------------------------------------------------------------------------
extern "C" void kernel_launch(void* const* d_in, const int* in_sizes, int n_in,
                              void* d_out, int out_size, void* d_ws, size_t ws_size,
                              hipStream_t stream) {
  const float* key   = (const float*)d_in[0];
  const float* value = (const float*)d_in[1];
  const float* query = (const float*)d_in[2];
  const float* Wq = (const float*)d_in[3];
  const float* Wk = (const float*)d_in[4];
  const float* Wv = (const float*)d_in[5];
  const float* Wo = (const float*)d_in[6];
  const float* W1 = (const float*)d_in[7];
  const float* b1 = (const float*)d_in[8];
  const float* W2 = (const float*)d_in[9];
  const float* b2 = (const float*)d_in[10];
  const float* g1 = (const float*)d_in[11];
  const float* be1 = (const float*)d_in[12];
  const float* g2 = (const float*)d_in[13];
  const float* be2 = (const float*)d_in[14];
  float* out = (float*)d_out;

  bf16_t* ws = (bf16_t*)d_ws;
  const size_t NB = (size_t)B_ * S_ * D_;  // 4 Mi elems
  bf16_t* qpe = ws + 0 * NB;
  bf16_t* kpe = ws + 1 * NB;
  bf16_t* vpe = ws + 2 * NB;
  bf16_t* Qp  = ws + 3 * NB;
  bf16_t* Kp  = ws + 4 * NB;
  bf16_t* Vt  = ws + 5 * NB;   // [B][D][S] transposed V projection
  bf16_t* ctx = kpe;  // dead after QKV gemm
  bf16_t* ao  = vpe;  // dead after QKV gemm
  bf16_t* x1  = Qp;   // dead after attention
  bf16_t* hh  = Kp;   // dead after attention
  bf16_t* ff  = Vt;   // dead after attention

  // bf16 weights live in d_out (16 MB; 6 x 2 MB used, overwritten by final LN)
  bf16_t* wb = (bf16_t*)d_out;
  const size_t WN = (size_t)D_ * D_;
  bf16_t* Wqb = wb + 0 * WN;
  bf16_t* Wkb = wb + 1 * WN;
  bf16_t* Wvb = wb + 2 * WN;
  bf16_t* Wob = wb + 3 * WN;
  bf16_t* W1b = wb + 4 * WN;
  bf16_t* W2b = wb + 5 * WN;

  dim3 ggrid(D_ / 64, (B_ * S_) / 128);        // 16 x 32

  cvtw_kernel<<<dim3(D_ * D_ / 1024, 6), 256, 0, stream>>>(
      Wq, Wk, Wv, Wo, W1, W2, wb);
  addpe_kernel<<<B_ * S_, 256, 0, stream>>>(query, key, value, qpe, kpe, vpe);

  gemm2p<3><<<dim3(D_ / 64, (B_ * S_) / 128, 3), 256, 0, stream>>>(
      qpe, kpe, vpe, Wqb, Wkb, Wvb, nullptr, Qp, Kp, Vt);

  attn_kernel<<<dim3(S_ / 64, B_ * H_), 256, 0, stream>>>(Qp, Kp, Vt, ctx);

  gemm2p<0><<<ggrid, 256, 0, stream>>>(ctx, nullptr, nullptr, Wob, nullptr, nullptr,
                                       nullptr, ao, nullptr, nullptr);
  add_ln_kernel<bf16_t><<<B_ * S_, 256, 0, stream>>>(ao, qpe, g1, be1, x1);

  gemm2p<2><<<ggrid, 256, 0, stream>>>(x1, nullptr, nullptr, W1b, nullptr, nullptr,
                                       b1, hh, nullptr, nullptr);
  gemm2p<1><<<ggrid, 256, 0, stream>>>(hh, nullptr, nullptr, W2b, nullptr, nullptr,
                                       b2, ff, nullptr, nullptr);
  add_ln_kernel<float><<<B_ * S_, 256, 0, stream>>>(ff, x1, g2, be2, out);
}

// Round 6
// 246.053 us; speedup vs baseline: 1.7962x; 1.0363x over previous
//
#include <hip/hip_runtime.h>
#include <hip/hip_bf16.h>
#include <math.h>

// ---------------------------------------------------------------------------
// TransformerLayer: B=2 S=2048 D=1024 H=16 HD=64. I/O f32, internals bf16.
// Round 6: attention softmax surgery — (1) l via MFMA-ones accumulator (no
// shuffle sum-reduce), (2) exp2-domain scores (single v_exp_f32 per score),
// (3) hoisted swizzle addresses + unroll-2 (compile-time dbuf indices).
// ---------------------------------------------------------------------------

#define B_ 2
#define S_ 2048
#define D_ 1024
#define H_ 16
#define HD_ 64

typedef __bf16 bf16_t;
typedef __bf16 bf16x8 __attribute__((ext_vector_type(8)));
typedef __bf16 bf16x4v __attribute__((ext_vector_type(4)));
typedef float f32x4 __attribute__((ext_vector_type(4)));

__device__ __forceinline__ f32x4 mfma16(bf16x8 a, bf16x8 b, f32x4 c) {
  return __builtin_amdgcn_mfma_f32_16x16x32_bf16(a, b, c, 0, 0, 0);
}

// global -> LDS direct copy, 16B/lane. LDS dest: wave-uniform base + lane*16.
__device__ __forceinline__ void gload_lds16(const bf16_t* g, bf16_t* l) {
  __builtin_amdgcn_global_load_lds((const __attribute__((address_space(1))) void*)g,
                                   (__attribute__((address_space(3))) void*)l,
                                   16, 0, 0);
}

// ---------------------------------------------------------------------------
// Kernel 0: convert 6 f32 weight matrices (D x D) to bf16, contiguous in dst.
// ---------------------------------------------------------------------------
__global__ __launch_bounds__(256) void cvtw_kernel(
    const float* __restrict__ w0, const float* __restrict__ w1,
    const float* __restrict__ w2, const float* __restrict__ w3,
    const float* __restrict__ w4, const float* __restrict__ w5,
    bf16_t* __restrict__ dst) {
  const int wsel = blockIdx.y;
  const float* src = wsel == 0 ? w0 : wsel == 1 ? w1 : wsel == 2 ? w2
                   : wsel == 3 ? w3 : wsel == 4 ? w4 : w5;
  const size_t off = (size_t)blockIdx.x * 1024 + threadIdx.x * 4;
  float4 v = *(const float4*)(src + off);
  bf16x4v r;
  r[0] = (bf16_t)v.x; r[1] = (bf16_t)v.y; r[2] = (bf16_t)v.z; r[3] = (bf16_t)v.w;
  *(bf16x4v*)(dst + (size_t)wsel * (D_ * D_) + off) = r;
}

// ---------------------------------------------------------------------------
// Kernel 1: positional encoding + add; f32 in -> bf16 out (q,k,v one pass).
// ---------------------------------------------------------------------------
__global__ __launch_bounds__(256) void addpe_kernel(
    const float* __restrict__ q, const float* __restrict__ k,
    const float* __restrict__ v,
    bf16_t* __restrict__ qo, bf16_t* __restrict__ ko, bf16_t* __restrict__ vo) {
  const int row = blockIdx.x;            // b*S + s
  const int s = row & (S_ - 1);
  const int d0 = threadIdx.x * 4;
  const size_t base = (size_t)row * D_ + d0;
  float pe[4];
#pragma unroll
  for (int p = 0; p < 2; ++p) {
    float div = __expf((float)(d0 + 2 * p) * -0.008994473019508f);
    float ang = (float)s * div;
    pe[2 * p]     = sinf(ang);
    pe[2 * p + 1] = cosf(ang);
  }
  float4 qv = *(const float4*)&q[base];
  float4 kv = *(const float4*)&k[base];
  float4 vv = *(const float4*)&v[base];
  bf16x4v qr, kr, vr;
  qr[0] = (bf16_t)(qv.x + pe[0]); qr[1] = (bf16_t)(qv.y + pe[1]);
  qr[2] = (bf16_t)(qv.z + pe[2]); qr[3] = (bf16_t)(qv.w + pe[3]);
  kr[0] = (bf16_t)(kv.x + pe[0]); kr[1] = (bf16_t)(kv.y + pe[1]);
  kr[2] = (bf16_t)(kv.z + pe[2]); kr[3] = (bf16_t)(kv.w + pe[3]);
  vr[0] = (bf16_t)(vv.x + pe[0]); vr[1] = (bf16_t)(vv.y + pe[1]);
  vr[2] = (bf16_t)(vv.z + pe[2]); vr[3] = (bf16_t)(vv.w + pe[3]);
  *(bf16x4v*)&qo[base] = qr;
  *(bf16x4v*)&ko[base] = kr;
  *(bf16x4v*)&vo[base] = vr;
}

// ---------------------------------------------------------------------------
// Kernel 2: NT GEMM C[M=4096,N=1024] = A[M,1024] x W[1024,1024]^T, all bf16.
// Tile 128x64, BK=32, 4 waves (2x2, each 64x32). 2-phase dbuf, 1 barrier/iter,
// A and W staged via global_load_lds.
// MODE: 0 plain, 1 +bias, 2 +bias+relu, 3 QKV batched (z: 0=Q,1=K,2=V^T out)
// ---------------------------------------------------------------------------
template <int MODE>
__global__ __launch_bounds__(256) void gemm2p(
    const bf16_t* __restrict__ a0p, const bf16_t* __restrict__ a1p,
    const bf16_t* __restrict__ a2p,
    const bf16_t* __restrict__ w0p, const bf16_t* __restrict__ w1p,
    const bf16_t* __restrict__ w2p,
    const float* __restrict__ bias,
    bf16_t* __restrict__ o0, bf16_t* __restrict__ o1, bf16_t* __restrict__ o2) {
  constexpr int Kd = 1024, NT = Kd / 32;
  __shared__ alignas(16) bf16_t As[2][128 * 32];
  __shared__ alignas(16) bf16_t Bs[2][64 * 32];
  const int t = threadIdx.x, lane = t & 63, wid = t >> 6;
  const int m0 = blockIdx.y * 128, n0 = blockIdx.x * 64;

  const bf16_t* A = a0p;
  const bf16_t* Wb = w0p;
  if (MODE == 3) {
    if (blockIdx.z == 1) { A = a1p; Wb = w1p; }
    else if (blockIdx.z == 2) { A = a2p; Wb = w2p; }
  }

  const bf16_t* Asrc0 = A + (size_t)(m0 + wid * 16 + (lane >> 2)) * Kd + (lane & 3) * 8;
  const bf16_t* Asrc1 = Asrc0 + (size_t)64 * Kd;
  const bf16_t* Wsrc = Wb + (size_t)(n0 + wid * 16 + (lane >> 2)) * Kd + (lane & 3) * 8;

  const f32x4 zero = {0.f, 0.f, 0.f, 0.f};
  f32x4 acc[4][2];
#pragma unroll
  for (int m = 0; m < 4; ++m) { acc[m][0] = zero; acc[m][1] = zero; }

  gload_lds16(Asrc0, &As[0][wid * 512]);
  gload_lds16(Asrc1, &As[0][2048 + wid * 512]);
  gload_lds16(Wsrc,  &Bs[0][wid * 512]);

  const int wr = wid >> 1, wc = wid & 1;
#pragma unroll 2
  for (int kt = 0; kt < NT; ++kt) {
    __syncthreads();                       // tile kt resident (vm drained)
    const int cur = kt & 1, nxt = cur ^ 1;
    if (kt + 1 < NT) {
      const int k0 = (kt + 1) * 32;
      gload_lds16(Asrc0 + k0, &As[nxt][wid * 512]);
      gload_lds16(Asrc1 + k0, &As[nxt][2048 + wid * 512]);
      gload_lds16(Wsrc + k0,  &Bs[nxt][wid * 512]);
    }
    bf16x8 af[4], bfr[2];
#pragma unroll
    for (int m = 0; m < 4; ++m)
      af[m] = *(const bf16x8*)&As[cur][(wr * 64 + m * 16 + (lane & 15)) * 32 + (lane >> 4) * 8];
#pragma unroll
    for (int n = 0; n < 2; ++n)
      bfr[n] = *(const bf16x8*)&Bs[cur][(wc * 32 + n * 16 + (lane & 15)) * 32 + (lane >> 4) * 8];
#pragma unroll
    for (int m = 0; m < 4; ++m)
#pragma unroll
      for (int n = 0; n < 2; ++n)
        acc[m][n] = mfma16(af[m], bfr[n], acc[m][n]);
  }

  const int rbase = m0 + wr * 64 + (lane >> 4) * 4;
  const int cbase = n0 + wc * 32 + (lane & 15);
  if (MODE == 3 && blockIdx.z == 2) {
#pragma unroll
    for (int n = 0; n < 2; ++n) {
      const int col = cbase + n * 16;
#pragma unroll
      for (int m = 0; m < 4; ++m)
#pragma unroll
        for (int r = 0; r < 4; ++r) {
          const int row = rbase + m * 16 + r;
          const int bb = row >> 11, ss = row & (S_ - 1);
          o2[(size_t)bb * D_ * S_ + (size_t)col * S_ + ss] = (bf16_t)acc[m][n][r];
        }
    }
  } else {
    bf16_t* C = o0;
    if (MODE == 3 && blockIdx.z == 1) C = o1;
#pragma unroll
    for (int n = 0; n < 2; ++n) {
      const int col = cbase + n * 16;
      float bv = (MODE == 1 || MODE == 2) ? bias[col] : 0.f;
#pragma unroll
      for (int m = 0; m < 4; ++m)
#pragma unroll
        for (int r = 0; r < 4; ++r) {
          float vv = acc[m][n][r] + bv;
          if (MODE == 2) vv = fmaxf(vv, 0.f);
          C[(size_t)(rbase + m * 16 + r) * D_ + col] = (bf16_t)vv;
        }
    }
  }
}

// ---------------------------------------------------------------------------
// Kernel 3: flash attention. grid (S/64, B*H), 4 waves x 16 q-rows, KVBLK=64.
// exp2-domain scores (Q pre-scaled by 0.125*log2e), defer-max (THR=11.54),
// l accumulated by MFMA with a ones-B-fragment (no shuffle sum-reduce),
// swizzled gload_lds K/Vt staging, 2-phase dbuf, hoisted LDS addresses.
// ---------------------------------------------------------------------------
__global__ __launch_bounds__(256) void attn_kernel(
    const bf16_t* __restrict__ Q, const bf16_t* __restrict__ K,
    const bf16_t* __restrict__ Vt, bf16_t* __restrict__ O) {
  constexpr int NT = S_ / 64;
  constexpr float THR = 11.5416f;          // 8 * log2(e)
  __shared__ alignas(16) bf16_t Ks[2][64 * 64];
  __shared__ alignas(16) bf16_t Vs[2][64 * 64];
  __shared__ alignas(16) bf16_t Ps[4 * 16 * 72];
  const int t = threadIdx.x, lane = t & 63, wid = t >> 6;
  const int b = blockIdx.y >> 4, h = blockIdx.y & 15;
  const int q0 = blockIdx.x * 64 + wid * 16;
  const int g = lane >> 4, c16 = lane & 15;

  // Q frags (A-op: row=c16=q, k=d=g*8+j), pre-scaled into exp2 domain
  const size_t rowQ = (size_t)(b * S_ + q0 + c16) * D_ + h * HD_ + g * 8;
  bf16x8 qa0 = *(const bf16x8*)&Q[rowQ];
  bf16x8 qa1 = *(const bf16x8*)&Q[rowQ + 32];
#pragma unroll
  for (int j = 0; j < 8; ++j) {
    qa0[j] = (bf16_t)((float)qa0[j] * (0.125f * 1.44269504f));
    qa1[j] = (bf16_t)((float)qa1[j] * (0.125f * 1.44269504f));
  }

  bf16x8 onesb;
#pragma unroll
  for (int j = 0; j < 8; ++j) onesb[j] = (bf16_t)1.0f;

  const f32x4 zero = {0.f, 0.f, 0.f, 0.f};
  f32x4 ctx[4] = {zero, zero, zero, zero};
  f32x4 lf = zero;                         // l[q=g*4+r] via MFMA-ones
  float mrow[4] = {-1e30f, -1e30f, -1e30f, -1e30f};

  // hoisted swizzled LDS read offsets (all loop-invariant)
  int qk_addr[4][2];
#pragma unroll
  for (int kc = 0; kc < 4; ++kc) {
    const int krow = kc * 16 + c16;
    qk_addr[kc][0] = krow * 64 + ((0 + g) ^ (krow & 7)) * 8;
    qk_addr[kc][1] = krow * 64 + ((4 + g) ^ (krow & 7)) * 8;
  }
  int pv_vaddr[2][4];
#pragma unroll
  for (int ks = 0; ks < 2; ++ks)
#pragma unroll
    for (int n = 0; n < 4; ++n) {
      const int vrow = n * 16 + c16;
      pv_vaddr[ks][n] = vrow * 64 + ((ks * 4 + g) ^ (vrow & 7)) * 8;
    }
  bf16_t* const prb = &Ps[wid * 1152];
  const int ap0 = c16 * 72, ap1 = c16 * 72 + 32;

  // staging: wave w, chunk c covers tile-rows c*32 + w*8 + (lane>>3);
  // phys slot (lane&7) holds logical slot (lane&7)^(row&7)
  const int trow = wid * 8 + (lane >> 3);
  const int lslot = ((lane & 7) ^ ((lane >> 3) & 7)) * 8;
  const bf16_t* Ksrc0 = K + (size_t)(b * S_ + trow) * D_ + h * HD_ + lslot;
  const bf16_t* Ksrc1 = K + (size_t)(b * S_ + 32 + trow) * D_ + h * HD_ + lslot;
  const bf16_t* Vsrc0 = Vt + (size_t)b * D_ * S_ + (size_t)(h * HD_ + trow) * S_ + lslot;
  const bf16_t* Vsrc1 = Vt + (size_t)b * D_ * S_ + (size_t)(h * HD_ + 32 + trow) * S_ + lslot;

  gload_lds16(Ksrc0, &Ks[0][wid * 512]);
  gload_lds16(Ksrc1, &Ks[0][2048 + wid * 512]);
  gload_lds16(Vsrc0, &Vs[0][wid * 512]);
  gload_lds16(Vsrc1, &Vs[0][2048 + wid * 512]);

#pragma unroll 2
  for (int kt = 0; kt < NT; ++kt) {
    __syncthreads();                       // tile kt resident
    const int cur = kt & 1, nxt = cur ^ 1;
    if (kt + 1 < NT) {
      const size_t ko = (size_t)(kt + 1) * 64 * D_;
      gload_lds16(Ksrc0 + ko, &Ks[nxt][wid * 512]);
      gload_lds16(Ksrc1 + ko, &Ks[nxt][2048 + wid * 512]);
      const size_t vo = (size_t)(kt + 1) * 64;
      gload_lds16(Vsrc0 + vo, &Vs[nxt][wid * 512]);
      gload_lds16(Vsrc1 + vo, &Vs[nxt][2048 + wid * 512]);
    }

    // QK^T (exp2 domain): 4 key-frags x 2 d-halves
    f32x4 sf[4];
#pragma unroll
    for (int kc = 0; kc < 4; ++kc) {
      bf16x8 kb0 = *(const bf16x8*)&Ks[cur][qk_addr[kc][0]];
      bf16x8 kb1 = *(const bf16x8*)&Ks[cur][qk_addr[kc][1]];
      f32x4 z = zero;
      z = mfma16(qa0, kb0, z);
      z = mfma16(qa1, kb1, z);
      sf[kc] = z;
    }

    // defer-max from unreduced per-lane maxima (wave-uniform decision)
    float lmx[4];
#pragma unroll
    for (int r = 0; r < 4; ++r)
      lmx[r] = fmaxf(fmaxf(sf[0][r], sf[1][r]), fmaxf(sf[2][r], sf[3][r]));
    const bool needl = (lmx[0] > mrow[0] + THR) | (lmx[1] > mrow[1] + THR) |
                       (lmx[2] > mrow[2] + THR) | (lmx[3] > mrow[3] + THR);
    if (__any(needl)) {
#pragma unroll
      for (int r = 0; r < 4; ++r) {
        float mx = lmx[r];
#pragma unroll
        for (int o = 1; o < 16; o <<= 1) mx = fmaxf(mx, __shfl_xor(mx, o));
        float mnew = fmaxf(mrow[r], mx);
        float scl = exp2f(mrow[r] - mnew);
        lf[r] *= scl;
#pragma unroll
        for (int n = 0; n < 4; ++n) ctx[n][r] *= scl;
        mrow[r] = mnew;
      }
    }

    // P = exp2(s - m), store to padded LDS (row q, cols = keys)
#pragma unroll
    for (int r = 0; r < 4; ++r) {
      bf16_t* pr = prb + (g * 4 + r) * 72 + c16;
      pr[0]  = (bf16_t)exp2f(sf[0][r] - mrow[r]);
      pr[16] = (bf16_t)exp2f(sf[1][r] - mrow[r]);
      pr[32] = (bf16_t)exp2f(sf[2][r] - mrow[r]);
      pr[48] = (bf16_t)exp2f(sf[3][r] - mrow[r]);
    }

    // PV + l: A = P[q][k], B = V^T frags (+ ones frag for l)
#pragma unroll
    for (int ks = 0; ks < 2; ++ks) {
      bf16x8 ap = *(const bf16x8*)&Ps[wid * 1152 + (ks ? ap1 : ap0) + g * 8];
      lf = mfma16(ap, onesb, lf);
#pragma unroll
      for (int n = 0; n < 4; ++n) {
        bf16x8 vb = *(const bf16x8*)&Vs[cur][pv_vaddr[ks][n]];
        ctx[n] = mfma16(ap, vb, ctx[n]);
      }
    }
  }

  // write (D-frag: row=g*4+r, col=n*16+c16); lf[r] = l for row g*4+r
#pragma unroll
  for (int r = 0; r < 4; ++r) {
    float inv = 1.f / lf[r];
    const size_t ro = (size_t)(b * S_ + q0 + g * 4 + r) * D_ + h * HD_ + c16;
#pragma unroll
    for (int n = 0; n < 4; ++n)
      O[ro + n * 16] = (bf16_t)(ctx[n][r] * inv);
  }
}

// ---------------------------------------------------------------------------
// Kernel 4: out = LayerNorm(a + res) * g + b.  a,res bf16; g,b f32.
// ---------------------------------------------------------------------------
template <typename OUT>
__global__ __launch_bounds__(256) void add_ln_kernel(
    const bf16_t* __restrict__ a, const bf16_t* __restrict__ res,
    const float* __restrict__ g, const float* __restrict__ be,
    OUT* __restrict__ out) {
  const int t = threadIdx.x;
  const int d0 = t * 4;
  const size_t base = (size_t)blockIdx.x * D_ + d0;
  float x[4];
  float s1 = 0.f, s2 = 0.f;
#pragma unroll
  for (int e = 0; e < 4; ++e) {
    x[e] = (float)a[base + e] + (float)res[base + e];
    s1 += x[e];
    s2 += x[e] * x[e];
  }
#pragma unroll
  for (int o = 32; o > 0; o >>= 1) {
    s1 += __shfl_down(s1, o);
    s2 += __shfl_down(s2, o);
  }
  __shared__ float red[8];
  const int lane = t & 63, wid = t >> 6;
  if (lane == 0) { red[wid] = s1; red[4 + wid] = s2; }
  __syncthreads();
  if (t == 0) {
    float t1 = red[0] + red[1] + red[2] + red[3];
    float t2 = red[4] + red[5] + red[6] + red[7];
    float mu = t1 * (1.f / D_);
    float var = t2 * (1.f / D_) - mu * mu;
    red[0] = mu;
    red[1] = rsqrtf(var + 1e-5f);
  }
  __syncthreads();
  const float mu = red[0], rstd = red[1];
#pragma unroll
  for (int e = 0; e < 4; ++e)
    out[base + e] = (OUT)((x[e] - mu) * rstd * g[d0 + e] + be[d0 + e]);
}

// ---------------------------------------------------------------------------
extern "C" void kernel_launch(void* const* d_in, const int* in_sizes, int n_in,
                              void* d_out, int out_size, void* d_ws, size_t ws_size,
                              hipStream_t stream) {
  const float* key   = (const float*)d_in[0];
  const float* value = (const float*)d_in[1];
  const float* query = (const float*)d_in[2];
  const float* Wq = (const float*)d_in[3];
  const float* Wk = (const float*)d_in[4];
  const float* Wv = (const float*)d_in[5];
  const float* Wo = (const float*)d_in[6];
  const float* W1 = (const float*)d_in[7];
  const float* b1 = (const float*)d_in[8];
  const float* W2 = (const float*)d_in[9];
  const float* b2 = (const float*)d_in[10];
  const float* g1 = (const float*)d_in[11];
  const float* be1 = (const float*)d_in[12];
  const float* g2 = (const float*)d_in[13];
  const float* be2 = (const float*)d_in[14];
  float* out = (float*)d_out;

  bf16_t* ws = (bf16_t*)d_ws;
  const size_t NB = (size_t)B_ * S_ * D_;  // 4 Mi elems
  bf16_t* qpe = ws + 0 * NB;
  bf16_t* kpe = ws + 1 * NB;
  bf16_t* vpe = ws + 2 * NB;
  bf16_t* Qp  = ws + 3 * NB;
  bf16_t* Kp  = ws + 4 * NB;
  bf16_t* Vt  = ws + 5 * NB;   // [B][D][S] transposed V projection
  bf16_t* ctx = kpe;  // dead after QKV gemm
  bf16_t* ao  = vpe;  // dead after QKV gemm
  bf16_t* x1  = Qp;   // dead after attention
  bf16_t* hh  = Kp;   // dead after attention
  bf16_t* ff  = Vt;   // dead after attention

  // bf16 weights live in d_out (16 MB; 6 x 2 MB used, overwritten by final LN)
  bf16_t* wb = (bf16_t*)d_out;
  const size_t WN = (size_t)D_ * D_;
  bf16_t* Wqb = wb + 0 * WN;
  bf16_t* Wkb = wb + 1 * WN;
  bf16_t* Wvb = wb + 2 * WN;
  bf16_t* Wob = wb + 3 * WN;
  bf16_t* W1b = wb + 4 * WN;
  bf16_t* W2b = wb + 5 * WN;

  dim3 ggrid(D_ / 64, (B_ * S_) / 128);        // 16 x 32

  cvtw_kernel<<<dim3(D_ * D_ / 1024, 6), 256, 0, stream>>>(
      Wq, Wk, Wv, Wo, W1, W2, wb);
  addpe_kernel<<<B_ * S_, 256, 0, stream>>>(query, key, value, qpe, kpe, vpe);

  gemm2p<3><<<dim3(D_ / 64, (B_ * S_) / 128, 3), 256, 0, stream>>>(
      qpe, kpe, vpe, Wqb, Wkb, Wvb, nullptr, Qp, Kp, Vt);

  attn_kernel<<<dim3(S_ / 64, B_ * H_), 256, 0, stream>>>(Qp, Kp, Vt, ctx);

  gemm2p<0><<<ggrid, 256, 0, stream>>>(ctx, nullptr, nullptr, Wob, nullptr, nullptr,
                                       nullptr, ao, nullptr, nullptr);
  add_ln_kernel<bf16_t><<<B_ * S_, 256, 0, stream>>>(ao, qpe, g1, be1, x1);

  gemm2p<2><<<ggrid, 256, 0, stream>>>(x1, nullptr, nullptr, W1b, nullptr, nullptr,
                                       b1, hh, nullptr, nullptr);
  gemm2p<1><<<ggrid, 256, 0, stream>>>(hh, nullptr, nullptr, W2b, nullptr, nullptr,
                                       b2, ff, nullptr, nullptr);
  add_ln_kernel<float><<<B_ * S_, 256, 0, stream>>>(ff, x1, g2, be2, out);
}